// Round 1
// baseline (1200.830 us; speedup 1.0000x reference)
//
#include <hip/hip_runtime.h>
#include <stdint.h>

typedef unsigned short u16;
typedef unsigned int u32;
typedef __bf16 bf16x8 __attribute__((ext_vector_type(8)));
typedef float f32x4 __attribute__((ext_vector_type(4)));

#define S_LEN 2048
#define BATCH 32
#define DIM 400           // d_model (rgb/pose feature dim)
#define HID 512           // hidden
#define KPAD 448          // 400 padded up to multiple of 64 for BK=32 loop
#define MROWS (BATCH * S_LEN)   // 65536
#define NB_CHUNK 8              // batches per scores chunk (chunk = 67MB, fits L3)
#define SCALE_QK 0.04419417382415922f  // 1/sqrt(512)

__device__ __forceinline__ u16 f2bf(float f) {
  u32 u = __float_as_uint(f);
  u = u + 0x7fffu + ((u >> 16) & 1u);   // RNE
  return (u16)(u >> 16);
}
__device__ __forceinline__ float bf2f(u16 h) {
  return __uint_as_float(((u32)h) << 16);
}

// async global->LDS, 16B per lane. LDS dest semantics: wave-uniform base + lane*16,
// which our tid*16 layout satisfies exactly.
__device__ __forceinline__ void async_cp16(const void* gp, const void* lp) {
  __builtin_amdgcn_global_load_lds(
      (const __attribute__((address_space(1))) void*)gp,
      (__attribute__((address_space(3))) void*)(uintptr_t)lp,
      16, 0, 0);
}

// C[M,N] = scale * (A[M,K] @ B[N,K]^T) + bias[col], bf16 in, fp32 acc, bf16 out.
// Block tile 128x128, BK=32, 4 waves in 2x2 (each wave 64x64 = 4x4 MFMA tiles).
// M, K multiples of 128/32; N tiles padded, store guarded by Nreal.
__global__ __launch_bounds__(256, 2)
void gemm_bt(const u16* __restrict__ A, const u16* __restrict__ B,
             u16* __restrict__ C, const float* __restrict__ bias,
             int K, int lda, int ldb, int ldc, int Nreal, float scale,
             long sA, long sB, long sC)
{
  __shared__ __align__(16) u16 As[128 * 32];  // 8KB
  __shared__ __align__(16) u16 Bs[128 * 32];  // 8KB
  const int tid = threadIdx.x;
  const int lane = tid & 63;
  const int w = tid >> 6;
  const int wm = w >> 1, wn = w & 1;
  const long m0 = (long)blockIdx.x * 128;
  const long n0 = (long)blockIdx.y * 128;
  const u16* Ab = A + (long)blockIdx.z * sA;
  const u16* Bb = B + (long)blockIdx.z * sB;
  u16* Cb = C + (long)blockIdx.z * sC;

  const int ar = tid >> 2;          // staging row within 64-row half
  const int ac = (tid & 3) * 8;     // staging 8-elem col segment

  f32x4 acc[4][4] = {};

  const int arow = wm * 64 + (lane & 15);
  const int brow = wn * 64 + (lane & 15);
  const int kk = lane >> 4;         // k-chunk 0..3 -> k offset kk*8

  for (int kt = 0; kt < K; kt += 32) {
    async_cp16(Ab + (m0 + ar) * (long)lda + kt + ac, As + tid * 8);
    async_cp16(Ab + (m0 + 64 + ar) * (long)lda + kt + ac, As + 2048 + tid * 8);
    async_cp16(Bb + (n0 + ar) * (long)ldb + kt + ac, Bs + tid * 8);
    async_cp16(Bb + (n0 + 64 + ar) * (long)ldb + kt + ac, Bs + 2048 + tid * 8);
    asm volatile("s_waitcnt vmcnt(0)" ::: "memory");
    __syncthreads();
    const bf16x8* Av = (const bf16x8*)As;
    const bf16x8* Bv = (const bf16x8*)Bs;
    bf16x8 af[4], bfr[4];
#pragma unroll
    for (int i = 0; i < 4; i++) af[i] = Av[(arow + i * 16) * 4 + kk];
#pragma unroll
    for (int j = 0; j < 4; j++) bfr[j] = Bv[(brow + j * 16) * 4 + kk];
#pragma unroll
    for (int i = 0; i < 4; i++)
#pragma unroll
      for (int j = 0; j < 4; j++)
        acc[i][j] = __builtin_amdgcn_mfma_f32_16x16x32_bf16(af[i], bfr[j], acc[i][j], 0, 0, 0);
    __syncthreads();
  }

  // C/D layout (m89-verified): col = lane&15, row = (lane>>4)*4 + r
#pragma unroll
  for (int j = 0; j < 4; j++) {
    const int col = (int)(n0 + wn * 64 + j * 16 + (lane & 15));
    if (col < Nreal) {
      const float bv = bias ? bias[col] : 0.0f;
#pragma unroll
      for (int i = 0; i < 4; i++) {
        const long row0 = m0 + wm * 64 + i * 16 + (lane >> 4) * 4;
#pragma unroll
        for (int r = 0; r < 4; r++) {
          Cb[(row0 + r) * (long)ldc + col] = f2bf(acc[i][j][r] * scale + bv);
        }
      }
    }
  }
}

// v[b][s][h] -> vT[b][h][s], 64x64 LDS tiles, uint4 global I/O both sides.
__global__ __launch_bounds__(256)
void transpose_hs(const u16* __restrict__ v, u16* __restrict__ vT)
{
  __shared__ u16 tile[64][66];   // pad 66 -> write-phase column gathers ~2-way
  const int b = blockIdx.z;
  const long s0 = (long)blockIdx.x * 64;
  const long h0 = (long)blockIdx.y * 64;
  const u16* vb = v + (long)b * S_LEN * HID;
  u16* vTb = vT + (long)b * HID * S_LEN;
  const int t = threadIdx.x;
  const int rr = t >> 3;          // 0..31
  const int cs = (t & 7) * 8;     // 0..56
#pragma unroll
  for (int p = 0; p < 2; p++) {
    const int r = p * 32 + rr;
    uint4 d = *(const uint4*)(vb + (s0 + r) * HID + h0 + cs);
    const u16* ds = (const u16*)&d;
#pragma unroll
    for (int j = 0; j < 8; j++) tile[r][cs + j] = ds[j];
  }
  __syncthreads();
#pragma unroll
  for (int p = 0; p < 2; p++) {
    const int hc = p * 32 + rr;
    __align__(16) u16 tmp[8];
#pragma unroll
    for (int j = 0; j < 8; j++) tmp[j] = tile[cs + j][hc];
    *(uint4*)(vTb + (h0 + hc) * S_LEN + s0 + cs) = *(const uint4*)tmp;
  }
}

// In-place softmax over rows of 2048 bf16. One 256-thread block per row.
__global__ __launch_bounds__(256)
void softmax_rows(u16* __restrict__ sc)
{
  const long row = blockIdx.x;
  u16* p = sc + row * (long)S_LEN;
  const int t = threadIdx.x;
  const int lane = t & 63, w = t >> 6;
  uint4 d = *(const uint4*)(p + t * 8);
  const u16* ds = (const u16*)&d;
  float x[8];
  float mx = -3.0e38f;
#pragma unroll
  for (int j = 0; j < 8; j++) { x[j] = bf2f(ds[j]); mx = fmaxf(mx, x[j]); }
#pragma unroll
  for (int o = 32; o > 0; o >>= 1) mx = fmaxf(mx, __shfl_xor(mx, o, 64));
  __shared__ float sm[4], ss[4];
  if (lane == 0) sm[w] = mx;
  __syncthreads();
  mx = fmaxf(fmaxf(sm[0], sm[1]), fmaxf(sm[2], sm[3]));
  float e[8], s = 0.f;
#pragma unroll
  for (int j = 0; j < 8; j++) { e[j] = __expf(x[j] - mx); s += e[j]; }
#pragma unroll
  for (int o = 32; o > 0; o >>= 1) s += __shfl_xor(s, o, 64);
  if (lane == 0) ss[w] = s;
  __syncthreads();
  s = ss[0] + ss[1] + ss[2] + ss[3];
  const float inv = 1.0f / s;
  __align__(16) u16 outv[8];
#pragma unroll
  for (int j = 0; j < 8; j++) outv[j] = f2bf(e[j] * inv);
  *(uint4*)(p + t * 8) = *(const uint4*)outv;
}

// x = rgb + gate*proj; LayerNorm(x)*gamma + beta -> fp32 out. One block per row.
__global__ __launch_bounds__(256)
void fuse_ln(const float* __restrict__ rgb, const u16* __restrict__ proj,
             const float* __restrict__ gatep, const float* __restrict__ gamma,
             const float* __restrict__ beta, float* __restrict__ out)
{
  const long row = blockIdx.x;
  const float* rp = rgb + row * DIM;
  const u16* pp = proj + row * DIM;
  float* op = out + row * DIM;
  const float g = gatep[0];
  const int t = threadIdx.x;
  const int lane = t & 63, w = t >> 6;
  const bool h1 = (t + 256) < DIM;
  float x0 = rp[t] + g * bf2f(pp[t]);
  float x1 = h1 ? (rp[t + 256] + g * bf2f(pp[t + 256])) : 0.f;
  float s = x0 + x1, q = x0 * x0 + x1 * x1;
#pragma unroll
  for (int o = 32; o > 0; o >>= 1) { s += __shfl_xor(s, o, 64); q += __shfl_xor(q, o, 64); }
  __shared__ float rs[4], rq[4];
  if (lane == 0) { rs[w] = s; rq[w] = q; }
  __syncthreads();
  s = rs[0] + rs[1] + rs[2] + rs[3];
  q = rq[0] + rq[1] + rq[2] + rq[3];
  const float mean = s * (1.0f / DIM);
  const float var = q * (1.0f / DIM) - mean * mean;
  const float rstd = rsqrtf(var + 1e-5f);
  op[t] = (x0 - mean) * rstd * gamma[t] + beta[t];
  if (h1) op[t + 256] = (x1 - mean) * rstd * gamma[t + 256] + beta[t + 256];
}

// fp32 [rows,400] -> bf16 [rows,448], zero-padded cols 400..447.
__global__ __launch_bounds__(256)
void cvt_pad(const float* __restrict__ src, u16* __restrict__ dst)
{
  const long g = (long)blockIdx.x * 256 + threadIdx.x;   // one 8-col segment each
  const long row = g / 56;
  const int cs = (int)(g % 56) * 8;
  __align__(16) u16 o[8];
#pragma unroll
  for (int j = 0; j < 8; j++) {
    const int c = cs + j;
    o[j] = f2bf(c < DIM ? src[row * DIM + c] : 0.0f);
  }
  *(uint4*)(dst + row * KPAD + cs) = *(const uint4*)o;
}

// W [400,512] fp32 -> WT [512,448] bf16 (transposed, K zero-padded)
__global__ __launch_bounds__(256)
void cvt_wT(const float* __restrict__ W, u16* __restrict__ WT)
{
  const int g = blockIdx.x * 256 + threadIdx.x;  // 512*448 exact
  const int n = g / KPAD;
  const int kc = g % KPAD;
  WT[g] = f2bf(kc < DIM ? W[(long)kc * HID + n] : 0.0f);
}

// Wp [512,400] fp32 -> WT [512(N pad),512(K)] bf16 (transposed, N zero-padded)
__global__ __launch_bounds__(256)
void cvt_wpT(const float* __restrict__ Wp, u16* __restrict__ WT)
{
  const int g = blockIdx.x * 256 + threadIdx.x;  // 512*512 exact
  const int n = g / HID;
  const int kc = g % HID;
  WT[g] = f2bf(n < DIM ? Wp[(long)kc * DIM + n] : 0.0f);
}

extern "C" void kernel_launch(void* const* d_in, const int* in_sizes, int n_in,
                              void* d_out, int out_size, void* d_ws, size_t ws_size,
                              hipStream_t stream)
{
  const float* rgb  = (const float*)d_in[0];
  const float* pose = (const float*)d_in[1];
  const float* Wq   = (const float*)d_in[2];
  const float* bq   = (const float*)d_in[3];
  const float* Wk   = (const float*)d_in[4];
  const float* bk   = (const float*)d_in[5];
  const float* Wv   = (const float*)d_in[6];
  const float* bv   = (const float*)d_in[7];
  const float* Wp   = (const float*)d_in[8];
  const float* bp   = (const float*)d_in[9];
  const float* gam  = (const float*)d_in[10];
  const float* bet  = (const float*)d_in[11];
  const float* gate = (const float*)d_in[12];
  float* outp = (float*)d_out;
  char* ws = (char*)d_ws;

  // Workspace layout (~390 MB total, with lifetime-based reuse):
  //  [0, 58.7M)        rgbp (dies after QKV)   } reused later by outb/projb
  //  [58.7M, 117.4M)   posep (dies after QKV)  }
  //  outb  = [0, 67.1M)        written in PV GEMM (after rgbp/posep dead)
  //  projb = [67.1M, 119.5M)
  //  [119.5M, 121.4M)  WqT/WkT/WvT/WpT
  //  [121.4M, 188.5M)  q   ; [188.5M, 255.7M) k
  //  [255.7M, 322.8M)  v  -> reused as scores chunk after transpose
  //  [322.8M, 389.9M)  vT
  const size_t SZ_PAD = (size_t)MROWS * KPAD * 2;        // 58,720,256
  const size_t SZ_SH  = (size_t)MROWS * HID * 2;         // 67,108,864
  u16* rgbp  = (u16*)(ws + 0);
  u16* posep = (u16*)(ws + SZ_PAD);
  u16* outb  = (u16*)(ws + 0);          // reuse of rgbp/posep zone
  u16* projb = (u16*)(ws + SZ_SH);
  size_t off = 119537664;
  u16* wqT = (u16*)(ws + off); off += (size_t)HID * KPAD * 2;
  u16* wkT = (u16*)(ws + off); off += (size_t)HID * KPAD * 2;
  u16* wvT = (u16*)(ws + off); off += (size_t)HID * KPAD * 2;
  u16* wpT = (u16*)(ws + off); off += (size_t)HID * HID * 2;
  u16* qb  = (u16*)(ws + off); off += SZ_SH;
  u16* kb  = (u16*)(ws + off); off += SZ_SH;
  u16* vb  = (u16*)(ws + off);
  u16* scb = vb;                        // scores chunk overlays v (v dead post-transpose)
  off += SZ_SH;
  u16* vTb = (u16*)(ws + off); off += SZ_SH;

  // --- input conversion / packing ---
  cvt_pad<<<14336, 256, 0, stream>>>(rgb, rgbp);
  cvt_pad<<<14336, 256, 0, stream>>>(pose, posep);
  cvt_wT<<<896, 256, 0, stream>>>(Wq, wqT);
  cvt_wT<<<896, 256, 0, stream>>>(Wk, wkT);
  cvt_wT<<<896, 256, 0, stream>>>(Wv, wvT);
  cvt_wpT<<<1024, 256, 0, stream>>>(Wp, wpT);

  // --- QKV projections: [65536,448] @ [512,448]^T ---
  dim3 gQ(MROWS / 128, HID / 128, 1);   // (512,4)
  gemm_bt<<<gQ, 256, 0, stream>>>(rgbp,  wqT, qb, bq, KPAD, KPAD, KPAD, HID, HID, 1.0f, 0, 0, 0);
  gemm_bt<<<gQ, 256, 0, stream>>>(posep, wkT, kb, bk, KPAD, KPAD, KPAD, HID, HID, 1.0f, 0, 0, 0);
  gemm_bt<<<gQ, 256, 0, stream>>>(posep, wvT, vb, bv, KPAD, KPAD, KPAD, HID, HID, 1.0f, 0, 0, 0);

  // --- v -> vT per batch ---
  dim3 gT(S_LEN / 64, HID / 64, BATCH); // (32,8,32)
  transpose_hs<<<gT, 256, 0, stream>>>(vb, vTb);

  // --- attention, chunked over batches (scores chunk stays L3-resident) ---
  const long sSH = (long)S_LEN * HID;     // 1,048,576
  const long sSS = (long)S_LEN * S_LEN;   // 4,194,304
  for (int c = 0; c < BATCH / NB_CHUNK; c++) {
    const size_t bo = (size_t)c * NB_CHUNK;
    dim3 g2(S_LEN / 128, S_LEN / 128, NB_CHUNK);  // (16,16,8)
    gemm_bt<<<g2, 256, 0, stream>>>(qb + bo * sSH, kb + bo * sSH, scb, nullptr,
                                    HID, HID, HID, S_LEN, S_LEN, SCALE_QK, sSH, sSH, sSS);
    softmax_rows<<<NB_CHUNK * S_LEN, 256, 0, stream>>>(scb);
    dim3 g4(S_LEN / 128, HID / 128, NB_CHUNK);    // (16,4,8)
    gemm_bt<<<g4, 256, 0, stream>>>(scb, vTb + bo * sSH, outb + bo * sSH, nullptr,
                                    S_LEN, S_LEN, S_LEN, HID, HID, 1.0f, sSS, sSH, sSH);
  }

  // --- output projection: [65536,512] @ [512(400 pad),512]^T + bp ---
  gemm_bt<<<gQ, 256, 0, stream>>>(outb, wpT, projb, bp, HID, HID, HID, DIM, DIM, 1.0f, 0, 0, 0);

  // --- gated residual + LayerNorm (fp32 rgb path keeps residual exact) ---
  fuse_ln<<<MROWS, 256, 0, stream>>>(rgb, projb, gate, gam, bet, outp);
}

// Round 2
// 1171.136 us; speedup vs baseline: 1.0254x; 1.0254x over previous
//
#include <hip/hip_runtime.h>
#include <stdint.h>

typedef unsigned short u16;
typedef unsigned int u32;
typedef __bf16 bf16x8 __attribute__((ext_vector_type(8)));
typedef float f32x4 __attribute__((ext_vector_type(4)));

#define S_LEN 2048
#define BATCH 32
#define DIM 400           // d_model (rgb/pose feature dim)
#define HID 512           // hidden
#define KPAD 448          // 400 padded up to multiple of 64 for BK=32 loop
#define MROWS (BATCH * S_LEN)   // 65536
#define NB_CHUNK 8              // batches per scores chunk (chunk = 67MB, fits L3)
#define SCALE_QK 0.04419417382415922f  // 1/sqrt(512)

__device__ __forceinline__ u16 f2bf(float f) {
  u32 u = __float_as_uint(f);
  u = u + 0x7fffu + ((u >> 16) & 1u);   // RNE
  return (u16)(u >> 16);
}
__device__ __forceinline__ float bf2f(u16 h) {
  return __uint_as_float(((u32)h) << 16);
}

// async global->LDS, 16B per lane. LDS dest semantics: wave-uniform base + lane*16,
// which our tid*16 layout satisfies exactly.
__device__ __forceinline__ void async_cp16(const void* gp, const void* lp) {
  __builtin_amdgcn_global_load_lds(
      (const __attribute__((address_space(1))) void*)gp,
      (__attribute__((address_space(3))) void*)(uintptr_t)lp,
      16, 0, 0);
}

// C[M,N] = scale * (A[M,K] @ B[N,K]^T) + bias[col], bf16 in, fp32 acc, bf16 out.
// Block tile 128x128, BK=32, 4 waves in 2x2 (each wave 64x64 = 4x4 MFMA tiles).
// M, K multiples of 128/32; N tiles padded, store guarded by Nreal.
// launch_bounds(256,3): cap VGPR ~170 -> 3 blocks/CU resident (m97 ran 164 VGPR).
__global__ __launch_bounds__(256, 3)
void gemm_bt(const u16* __restrict__ A, const u16* __restrict__ B,
             u16* __restrict__ C, const float* __restrict__ bias,
             int K, int lda, int ldb, int ldc, int Nreal, float scale,
             long sA, long sB, long sC)
{
  __shared__ __align__(16) u16 As[128 * 32];  // 8KB
  __shared__ __align__(16) u16 Bs[128 * 32];  // 8KB
  const int tid = threadIdx.x;
  const int lane = tid & 63;
  const int w = tid >> 6;
  const int wm = w >> 1, wn = w & 1;
  const long m0 = (long)blockIdx.x * 128;
  const long n0 = (long)blockIdx.y * 128;
  const u16* Ab = A + (long)blockIdx.z * sA;
  const u16* Bb = B + (long)blockIdx.z * sB;
  u16* Cb = C + (long)blockIdx.z * sC;

  const int ar = tid >> 2;          // staging row within 64-row half
  const int ac = (tid & 3) * 8;     // staging 8-elem col segment

  f32x4 acc[4][4] = {};

  const int arow = wm * 64 + (lane & 15);
  const int brow = wn * 64 + (lane & 15);
  const int kk = lane >> 4;         // k-chunk 0..3 -> k offset kk*8

  for (int kt = 0; kt < K; kt += 32) {
    async_cp16(Ab + (m0 + ar) * (long)lda + kt + ac, As + tid * 8);
    async_cp16(Ab + (m0 + 64 + ar) * (long)lda + kt + ac, As + 2048 + tid * 8);
    async_cp16(Bb + (n0 + ar) * (long)ldb + kt + ac, Bs + tid * 8);
    async_cp16(Bb + (n0 + 64 + ar) * (long)ldb + kt + ac, Bs + 2048 + tid * 8);
    asm volatile("s_waitcnt vmcnt(0)" ::: "memory");
    __syncthreads();
    const bf16x8* Av = (const bf16x8*)As;
    const bf16x8* Bv = (const bf16x8*)Bs;
    bf16x8 af[4], bfr[4];
#pragma unroll
    for (int i = 0; i < 4; i++) af[i] = Av[(arow + i * 16) * 4 + kk];
#pragma unroll
    for (int j = 0; j < 4; j++) bfr[j] = Bv[(brow + j * 16) * 4 + kk];
#pragma unroll
    for (int i = 0; i < 4; i++)
#pragma unroll
      for (int j = 0; j < 4; j++)
        acc[i][j] = __builtin_amdgcn_mfma_f32_16x16x32_bf16(af[i], bfr[j], acc[i][j], 0, 0, 0);
    __syncthreads();
  }

  // C/D layout (m89-verified): col = lane&15, row = (lane>>4)*4 + r
#pragma unroll
  for (int j = 0; j < 4; j++) {
    const int col = (int)(n0 + wn * 64 + j * 16 + (lane & 15));
    if (col < Nreal) {
      const float bv = bias ? bias[col] : 0.0f;
#pragma unroll
      for (int i = 0; i < 4; i++) {
        const long row0 = m0 + wm * 64 + i * 16 + (lane >> 4) * 4;
#pragma unroll
        for (int r = 0; r < 4; r++) {
          Cb[(row0 + r) * (long)ldc + col] = f2bf(acc[i][j][r] * scale + bv);
        }
      }
    }
  }
}

// v[b][s][h] -> vT[b][h][s], 64x64 LDS tiles, uint4 global I/O both sides.
__global__ __launch_bounds__(256)
void transpose_hs(const u16* __restrict__ v, u16* __restrict__ vT)
{
  __shared__ u16 tile[64][66];   // pad 66 -> write-phase column gathers ~2-way
  const int b = blockIdx.z;
  const long s0 = (long)blockIdx.x * 64;
  const long h0 = (long)blockIdx.y * 64;
  const u16* vb = v + (long)b * S_LEN * HID;
  u16* vTb = vT + (long)b * HID * S_LEN;
  const int t = threadIdx.x;
  const int rr = t >> 3;          // 0..31
  const int cs = (t & 7) * 8;     // 0..56
#pragma unroll
  for (int p = 0; p < 2; p++) {
    const int r = p * 32 + rr;
    uint4 d = *(const uint4*)(vb + (s0 + r) * HID + h0 + cs);
    const u16* ds = (const u16*)&d;
#pragma unroll
    for (int j = 0; j < 8; j++) tile[r][cs + j] = ds[j];
  }
  __syncthreads();
#pragma unroll
  for (int p = 0; p < 2; p++) {
    const int hc = p * 32 + rr;
    __align__(16) u16 tmp[8];
#pragma unroll
    for (int j = 0; j < 8; j++) tmp[j] = tile[cs + j][hc];
    *(uint4*)(vTb + (h0 + hc) * S_LEN + s0 + cs) = *(const uint4*)tmp;
  }
}

// In-place softmax over rows of 2048 bf16. One WAVE per row (no barriers),
// 4 rows per 256-thread block. Lane holds 32 elements (4x uint4).
__global__ __launch_bounds__(256)
void softmax_rows(u16* __restrict__ sc)
{
  const int w = threadIdx.x >> 6, lane = threadIdx.x & 63;
  const long row = (long)blockIdx.x * 4 + w;
  u16* p = sc + row * (long)S_LEN;

  uint4 d[4];
#pragma unroll
  for (int k = 0; k < 4; k++) d[k] = *(const uint4*)(p + (k * 64 + lane) * 8);

  float x[32];
  float mx = -3.0e38f;
#pragma unroll
  for (int k = 0; k < 4; k++) {
    const u16* ds = (const u16*)&d[k];
#pragma unroll
    for (int j = 0; j < 8; j++) { x[k * 8 + j] = bf2f(ds[j]); mx = fmaxf(mx, x[k * 8 + j]); }
  }
#pragma unroll
  for (int o = 32; o > 0; o >>= 1) mx = fmaxf(mx, __shfl_xor(mx, o, 64));

  float s = 0.f;
#pragma unroll
  for (int e = 0; e < 32; e++) { x[e] = __expf(x[e] - mx); s += x[e]; }
#pragma unroll
  for (int o = 32; o > 0; o >>= 1) s += __shfl_xor(s, o, 64);
  const float inv = 1.0f / s;

#pragma unroll
  for (int k = 0; k < 4; k++) {
    __align__(16) u16 outv[8];
#pragma unroll
    for (int j = 0; j < 8; j++) outv[j] = f2bf(x[k * 8 + j] * inv);
    *(uint4*)(p + (k * 64 + lane) * 8) = *(const uint4*)outv;
  }
}

// x = rgb + gate*proj; LayerNorm(x)*gamma + beta -> fp32 out.
// One WAVE per row (no barriers), 4 rows per block. Lanes 0..49 hold 8 cols each
// (2x float4 rgb, 1x uint4 proj); lanes 50..63 contribute zeros to the reduction.
__global__ __launch_bounds__(256)
void fuse_ln(const float* __restrict__ rgb, const u16* __restrict__ proj,
             const float* __restrict__ gatep, const float* __restrict__ gamma,
             const float* __restrict__ beta, float* __restrict__ out)
{
  const int w = threadIdx.x >> 6, lane = threadIdx.x & 63;
  const long row = (long)blockIdx.x * 4 + w;
  const float g = gatep[0];
  const float* rp = rgb + row * DIM;
  const u16* pp = proj + row * DIM;
  float* op = out + row * DIM;
  const int c = lane * 8;
  const bool act = (lane < 50);   // 50*8 = 400

  float x[8];
  float s = 0.f, q = 0.f;
  if (act) {
    float4 r0 = *(const float4*)(rp + c);
    float4 r1 = *(const float4*)(rp + c + 4);
    uint4 pv = *(const uint4*)(pp + c);
    const u16* pb = (const u16*)&pv;
    float rr[8] = {r0.x, r0.y, r0.z, r0.w, r1.x, r1.y, r1.z, r1.w};
#pragma unroll
    for (int j = 0; j < 8; j++) {
      x[j] = rr[j] + g * bf2f(pb[j]);
      s += x[j]; q += x[j] * x[j];
    }
  }
#pragma unroll
  for (int o = 32; o > 0; o >>= 1) { s += __shfl_xor(s, o, 64); q += __shfl_xor(q, o, 64); }
  const float mean = s * (1.0f / DIM);
  const float var = q * (1.0f / DIM) - mean * mean;
  const float rstd = rsqrtf(var + 1e-5f);
  if (act) {
    float4 ga0 = *(const float4*)(gamma + c);
    float4 ga1 = *(const float4*)(gamma + c + 4);
    float4 be0 = *(const float4*)(beta + c);
    float4 be1 = *(const float4*)(beta + c + 4);
    float4 o0, o1;
    o0.x = (x[0] - mean) * rstd * ga0.x + be0.x;
    o0.y = (x[1] - mean) * rstd * ga0.y + be0.y;
    o0.z = (x[2] - mean) * rstd * ga0.z + be0.z;
    o0.w = (x[3] - mean) * rstd * ga0.w + be0.w;
    o1.x = (x[4] - mean) * rstd * ga1.x + be1.x;
    o1.y = (x[5] - mean) * rstd * ga1.y + be1.y;
    o1.z = (x[6] - mean) * rstd * ga1.z + be1.z;
    o1.w = (x[7] - mean) * rstd * ga1.w + be1.w;
    *(float4*)(op + c) = o0;
    *(float4*)(op + c + 4) = o1;
  }
}

// fp32 [rows,400] -> bf16 [rows,448], zero-padded cols 400..447.
__global__ __launch_bounds__(256)
void cvt_pad(const float* __restrict__ src, u16* __restrict__ dst)
{
  const long g = (long)blockIdx.x * 256 + threadIdx.x;   // one 8-col segment each
  const long row = g / 56;
  const int cs = (int)(g % 56) * 8;
  __align__(16) u16 o[8];
#pragma unroll
  for (int j = 0; j < 8; j++) {
    const int c = cs + j;
    o[j] = f2bf(c < DIM ? src[row * DIM + c] : 0.0f);
  }
  *(uint4*)(dst + row * KPAD + cs) = *(const uint4*)o;
}

// W [400,512] fp32 -> WT [512,448] bf16 (transposed, K zero-padded)
__global__ __launch_bounds__(256)
void cvt_wT(const float* __restrict__ W, u16* __restrict__ WT)
{
  const int g = blockIdx.x * 256 + threadIdx.x;  // 512*448 exact
  const int n = g / KPAD;
  const int kc = g % KPAD;
  WT[g] = f2bf(kc < DIM ? W[(long)kc * HID + n] : 0.0f);
}

// Wp [512,400] fp32 -> WT [512(N pad),512(K)] bf16 (transposed, N zero-padded)
__global__ __launch_bounds__(256)
void cvt_wpT(const float* __restrict__ Wp, u16* __restrict__ WT)
{
  const int g = blockIdx.x * 256 + threadIdx.x;  // 512*512 exact
  const int n = g / HID;
  const int kc = g % HID;
  WT[g] = f2bf(n < DIM ? Wp[(long)kc * DIM + n] : 0.0f);
}

extern "C" void kernel_launch(void* const* d_in, const int* in_sizes, int n_in,
                              void* d_out, int out_size, void* d_ws, size_t ws_size,
                              hipStream_t stream)
{
  const float* rgb  = (const float*)d_in[0];
  const float* pose = (const float*)d_in[1];
  const float* Wq   = (const float*)d_in[2];
  const float* bq   = (const float*)d_in[3];
  const float* Wk   = (const float*)d_in[4];
  const float* bk   = (const float*)d_in[5];
  const float* Wv   = (const float*)d_in[6];
  const float* bv   = (const float*)d_in[7];
  const float* Wp   = (const float*)d_in[8];
  const float* bp   = (const float*)d_in[9];
  const float* gam  = (const float*)d_in[10];
  const float* bet  = (const float*)d_in[11];
  const float* gate = (const float*)d_in[12];
  float* outp = (float*)d_out;
  char* ws = (char*)d_ws;

  // Workspace layout (~390 MB total, with lifetime-based reuse):
  //  [0, 58.7M)        rgbp (dies after QKV)   } reused later by outb/projb
  //  [58.7M, 117.4M)   posep (dies after QKV)  }
  //  outb  = [0, 67.1M)        written in PV GEMM (after rgbp/posep dead)
  //  projb = [67.1M, 119.5M)
  //  [119.5M, 121.4M)  WqT/WkT/WvT/WpT
  //  [121.4M, 188.5M)  q   ; [188.5M, 255.7M) k
  //  [255.7M, 322.8M)  v  -> reused as scores chunk after transpose
  //  [322.8M, 389.9M)  vT
  const size_t SZ_PAD = (size_t)MROWS * KPAD * 2;        // 58,720,256
  const size_t SZ_SH  = (size_t)MROWS * HID * 2;         // 67,108,864
  u16* rgbp  = (u16*)(ws + 0);
  u16* posep = (u16*)(ws + SZ_PAD);
  u16* outb  = (u16*)(ws + 0);          // reuse of rgbp/posep zone
  u16* projb = (u16*)(ws + SZ_SH);
  size_t off = 119537664;
  u16* wqT = (u16*)(ws + off); off += (size_t)HID * KPAD * 2;
  u16* wkT = (u16*)(ws + off); off += (size_t)HID * KPAD * 2;
  u16* wvT = (u16*)(ws + off); off += (size_t)HID * KPAD * 2;
  u16* wpT = (u16*)(ws + off); off += (size_t)HID * HID * 2;
  u16* qb  = (u16*)(ws + off); off += SZ_SH;
  u16* kb  = (u16*)(ws + off); off += SZ_SH;
  u16* vb  = (u16*)(ws + off);
  u16* scb = vb;                        // scores chunk overlays v (v dead post-transpose)
  off += SZ_SH;
  u16* vTb = (u16*)(ws + off); off += SZ_SH;

  // --- input conversion / packing ---
  cvt_pad<<<14336, 256, 0, stream>>>(rgb, rgbp);
  cvt_pad<<<14336, 256, 0, stream>>>(pose, posep);
  cvt_wT<<<896, 256, 0, stream>>>(Wq, wqT);
  cvt_wT<<<896, 256, 0, stream>>>(Wk, wkT);
  cvt_wT<<<896, 256, 0, stream>>>(Wv, wvT);
  cvt_wpT<<<1024, 256, 0, stream>>>(Wp, wpT);

  // --- QKV projections: [65536,448] @ [512,448]^T ---
  dim3 gQ(MROWS / 128, HID / 128, 1);   // (512,4)
  gemm_bt<<<gQ, 256, 0, stream>>>(rgbp,  wqT, qb, bq, KPAD, KPAD, KPAD, HID, HID, 1.0f, 0, 0, 0);
  gemm_bt<<<gQ, 256, 0, stream>>>(posep, wkT, kb, bk, KPAD, KPAD, KPAD, HID, HID, 1.0f, 0, 0, 0);
  gemm_bt<<<gQ, 256, 0, stream>>>(posep, wvT, vb, bv, KPAD, KPAD, KPAD, HID, HID, 1.0f, 0, 0, 0);

  // --- v -> vT per batch ---
  dim3 gT(S_LEN / 64, HID / 64, BATCH); // (32,8,32)
  transpose_hs<<<gT, 256, 0, stream>>>(vb, vTb);

  // --- attention, chunked over batches (scores chunk stays L3-resident) ---
  const long sSH = (long)S_LEN * HID;     // 1,048,576
  const long sSS = (long)S_LEN * S_LEN;   // 4,194,304
  for (int c = 0; c < BATCH / NB_CHUNK; c++) {
    const size_t bo = (size_t)c * NB_CHUNK;
    dim3 g2(S_LEN / 128, S_LEN / 128, NB_CHUNK);  // (16,16,8)
    gemm_bt<<<g2, 256, 0, stream>>>(qb + bo * sSH, kb + bo * sSH, scb, nullptr,
                                    HID, HID, HID, S_LEN, S_LEN, SCALE_QK, sSH, sSH, sSS);
    softmax_rows<<<NB_CHUNK * S_LEN / 4, 256, 0, stream>>>(scb);
    dim3 g4(S_LEN / 128, HID / 128, NB_CHUNK);    // (16,4,8)
    gemm_bt<<<g4, 256, 0, stream>>>(scb, vTb + bo * sSH, outb + bo * sSH, nullptr,
                                    S_LEN, S_LEN, S_LEN, HID, HID, 1.0f, sSS, sSH, sSH);
  }

  // --- output projection: [65536,512] @ [512(400 pad),512]^T + bp ---
  gemm_bt<<<gQ, 256, 0, stream>>>(outb, wpT, projb, bp, HID, HID, HID, DIM, DIM, 1.0f, 0, 0, 0);

  // --- gated residual + LayerNorm (fp32 rgb path keeps residual exact) ---
  fuse_ln<<<MROWS / 4, 256, 0, stream>>>(rgb, projb, gate, gam, bet, outp);
}

// Round 3
// 1137.917 us; speedup vs baseline: 1.0553x; 1.0292x over previous
//
#include <hip/hip_runtime.h>
#include <stdint.h>

typedef unsigned short u16;
typedef unsigned int u32;
typedef __bf16 bf16x8 __attribute__((ext_vector_type(8)));
typedef float f32x4 __attribute__((ext_vector_type(4)));

#define S_LEN 2048
#define BATCH 32
#define DIM 400           // d_model (rgb/pose feature dim)
#define HID 512           // hidden
#define KPAD 448          // 400 padded up to multiple of 64 for BK=32 loop
#define MROWS (BATCH * S_LEN)   // 65536
#define NB_CHUNK 8              // batches per scores chunk (chunk = 67MB, fits L3)
#define SCALE_QK 0.04419417382415922f  // 1/sqrt(512)

__device__ __forceinline__ u16 f2bf(float f) {
  u32 u = __float_as_uint(f);
  u = u + 0x7fffu + ((u >> 16) & 1u);   // RNE
  return (u16)(u >> 16);
}
__device__ __forceinline__ float bf2f(u16 h) {
  return __uint_as_float(((u32)h) << 16);
}

// async global->LDS, 16B per lane. LDS dest semantics: wave-uniform base + lane*16,
// which our tid*16 layout satisfies exactly.
__device__ __forceinline__ void async_cp16(const void* gp, const void* lp) {
  __builtin_amdgcn_global_load_lds(
      (const __attribute__((address_space(1))) void*)gp,
      (__attribute__((address_space(3))) void*)(uintptr_t)lp,
      16, 0, 0);
}

// C[M,N] = scale * (A[M,K] @ B[N,K]^T) + bias[col], bf16 in, fp32 acc, bf16 out.
// Block tile 128x128, BK=32, 4 waves in 2x2 (each wave 64x64 = 4x4 MFMA tiles).
//
// K-loop: double-buffered LDS, raw s_barrier (NOT __syncthreads -- that emits
// s_waitcnt vmcnt(0) and drains the prefetch), prefetch tile t+1 issued before
// waiting vmcnt(4) for tile t. Schedule per iter t:
//   [stage t+1 into nxt] [vmcnt(4): t's 4 loads done, t+1's in flight]
//   [s_barrier: everyone staged]  [ds_read+MFMA on cur]
//   [s_barrier: everyone done reading cur -> safe to overwrite at t+2]
// Write-after-read on nxt: stage(t+1) happens after the end-of-(t-1) barrier,
// and all waves' t-1 ds_reads are consumed (lgkm-drained) before that barrier.
__global__ __launch_bounds__(256, 3)
void gemm_bt(const u16* __restrict__ A, const u16* __restrict__ B,
             u16* __restrict__ C, const float* __restrict__ bias,
             int K, int lda, int ldb, int ldc, int Nreal, float scale,
             long sA, long sB, long sC)
{
  __shared__ __align__(16) u16 As[2][128 * 32];  // 2 x 8KB
  __shared__ __align__(16) u16 Bs[2][128 * 32];  // 2 x 8KB
  const int tid = threadIdx.x;
  const int lane = tid & 63;
  const int w = tid >> 6;
  const int wm = w >> 1, wn = w & 1;
  const long m0 = (long)blockIdx.x * 128;
  const long n0 = (long)blockIdx.y * 128;
  const u16* Ab = A + (long)blockIdx.z * sA;
  const u16* Bb = B + (long)blockIdx.z * sB;
  u16* Cb = C + (long)blockIdx.z * sC;

  const int ar = tid >> 2;          // staging row within 64-row half
  const int ac = (tid & 3) * 8;     // staging 8-elem col segment

  // per-thread global staging pointers (advance by kt only)
  const u16* ga0 = Ab + (m0 + ar) * (long)lda + ac;
  const u16* ga1 = Ab + (m0 + 64 + ar) * (long)lda + ac;
  const u16* gb0 = Bb + (n0 + ar) * (long)ldb + ac;
  const u16* gb1 = Bb + (n0 + 64 + ar) * (long)ldb + ac;

  f32x4 acc[4][4] = {};

  const int arow = wm * 64 + (lane & 15);
  const int brow = wn * 64 + (lane & 15);
  const int kk = lane >> 4;         // k-chunk 0..3 -> k offset kk*8

  const int T = K >> 5;

  // prologue: stage tile 0 into buf 0
  async_cp16(ga0, &As[0][0] + tid * 8);
  async_cp16(ga1, &As[0][0] + 2048 + tid * 8);
  async_cp16(gb0, &Bs[0][0] + tid * 8);
  async_cp16(gb1, &Bs[0][0] + 2048 + tid * 8);

  for (int t = 0; t < T; t++) {
    const int cur = t & 1;
    if (t + 1 < T) {
      const int nxt = cur ^ 1;
      const int kt = (t + 1) << 5;
      async_cp16(ga0 + kt, &As[nxt][0] + tid * 8);
      async_cp16(ga1 + kt, &As[nxt][0] + 2048 + tid * 8);
      async_cp16(gb0 + kt, &Bs[nxt][0] + tid * 8);
      async_cp16(gb1 + kt, &Bs[nxt][0] + 2048 + tid * 8);
      asm volatile("s_waitcnt vmcnt(4)" ::: "memory");  // tile t staged (own)
    } else {
      asm volatile("s_waitcnt vmcnt(0)" ::: "memory");
    }
    asm volatile("s_barrier" ::: "memory");             // tile t staged (all waves)

    const bf16x8* Av = (const bf16x8*)&As[cur][0];
    const bf16x8* Bv = (const bf16x8*)&Bs[cur][0];
    bf16x8 af[4], bfr[4];
#pragma unroll
    for (int i = 0; i < 4; i++) af[i] = Av[(arow + i * 16) * 4 + kk];
#pragma unroll
    for (int j = 0; j < 4; j++) bfr[j] = Bv[(brow + j * 16) * 4 + kk];
#pragma unroll
    for (int i = 0; i < 4; i++)
#pragma unroll
      for (int j = 0; j < 4; j++)
        acc[i][j] = __builtin_amdgcn_mfma_f32_16x16x32_bf16(af[i], bfr[j], acc[i][j], 0, 0, 0);

    asm volatile("s_barrier" ::: "memory");             // all waves done reading cur
  }

  // C/D layout (m89-verified): col = lane&15, row = (lane>>4)*4 + r
#pragma unroll
  for (int j = 0; j < 4; j++) {
    const int col = (int)(n0 + wn * 64 + j * 16 + (lane & 15));
    if (col < Nreal) {
      const float bv = bias ? bias[col] : 0.0f;
#pragma unroll
      for (int i = 0; i < 4; i++) {
        const long row0 = m0 + wm * 64 + i * 16 + (lane >> 4) * 4;
#pragma unroll
        for (int r = 0; r < 4; r++) {
          Cb[(row0 + r) * (long)ldc + col] = f2bf(acc[i][j][r] * scale + bv);
        }
      }
    }
  }
}

// v[b][s][h] -> vT[b][h][s], 64x64 LDS tiles, uint4 global I/O both sides.
__global__ __launch_bounds__(256)
void transpose_hs(const u16* __restrict__ v, u16* __restrict__ vT)
{
  __shared__ u16 tile[64][66];   // pad 66 -> write-phase column gathers ~2-way
  const int b = blockIdx.z;
  const long s0 = (long)blockIdx.x * 64;
  const long h0 = (long)blockIdx.y * 64;
  const u16* vb = v + (long)b * S_LEN * HID;
  u16* vTb = vT + (long)b * HID * S_LEN;
  const int t = threadIdx.x;
  const int rr = t >> 3;          // 0..31
  const int cs = (t & 7) * 8;     // 0..56
#pragma unroll
  for (int p = 0; p < 2; p++) {
    const int r = p * 32 + rr;
    uint4 d = *(const uint4*)(vb + (s0 + r) * HID + h0 + cs);
    const u16* ds = (const u16*)&d;
#pragma unroll
    for (int j = 0; j < 8; j++) tile[r][cs + j] = ds[j];
  }
  __syncthreads();
#pragma unroll
  for (int p = 0; p < 2; p++) {
    const int hc = p * 32 + rr;
    __align__(16) u16 tmp[8];
#pragma unroll
    for (int j = 0; j < 8; j++) tmp[j] = tile[cs + j][hc];
    *(uint4*)(vTb + (h0 + hc) * S_LEN + s0 + cs) = *(const uint4*)tmp;
  }
}

// In-place softmax over rows of 2048 bf16. One WAVE per row (no barriers),
// 4 rows per 256-thread block. Lane holds 32 elements (4x uint4).
__global__ __launch_bounds__(256)
void softmax_rows(u16* __restrict__ sc)
{
  const int w = threadIdx.x >> 6, lane = threadIdx.x & 63;
  const long row = (long)blockIdx.x * 4 + w;
  u16* p = sc + row * (long)S_LEN;

  uint4 d[4];
#pragma unroll
  for (int k = 0; k < 4; k++) d[k] = *(const uint4*)(p + (k * 64 + lane) * 8);

  float x[32];
  float mx = -3.0e38f;
#pragma unroll
  for (int k = 0; k < 4; k++) {
    const u16* ds = (const u16*)&d[k];
#pragma unroll
    for (int j = 0; j < 8; j++) { x[k * 8 + j] = bf2f(ds[j]); mx = fmaxf(mx, x[k * 8 + j]); }
  }
#pragma unroll
  for (int o = 32; o > 0; o >>= 1) mx = fmaxf(mx, __shfl_xor(mx, o, 64));

  float s = 0.f;
#pragma unroll
  for (int e = 0; e < 32; e++) { x[e] = __expf(x[e] - mx); s += x[e]; }
#pragma unroll
  for (int o = 32; o > 0; o >>= 1) s += __shfl_xor(s, o, 64);
  const float inv = 1.0f / s;

#pragma unroll
  for (int k = 0; k < 4; k++) {
    __align__(16) u16 outv[8];
#pragma unroll
    for (int j = 0; j < 8; j++) outv[j] = f2bf(x[k * 8 + j] * inv);
    *(uint4*)(p + (k * 64 + lane) * 8) = *(const uint4*)outv;
  }
}

// x = rgb + gate*proj; LayerNorm(x)*gamma + beta -> fp32 out.
// One WAVE per row (no barriers), 4 rows per block. Lanes 0..49 hold 8 cols each
// (2x float4 rgb, 1x uint4 proj); lanes 50..63 contribute zeros to the reduction.
__global__ __launch_bounds__(256)
void fuse_ln(const float* __restrict__ rgb, const u16* __restrict__ proj,
             const float* __restrict__ gatep, const float* __restrict__ gamma,
             const float* __restrict__ beta, float* __restrict__ out)
{
  const int w = threadIdx.x >> 6, lane = threadIdx.x & 63;
  const long row = (long)blockIdx.x * 4 + w;
  const float g = gatep[0];
  const float* rp = rgb + row * DIM;
  const u16* pp = proj + row * DIM;
  float* op = out + row * DIM;
  const int c = lane * 8;
  const bool act = (lane < 50);   // 50*8 = 400

  float x[8];
  float s = 0.f, q = 0.f;
  if (act) {
    float4 r0 = *(const float4*)(rp + c);
    float4 r1 = *(const float4*)(rp + c + 4);
    uint4 pv = *(const uint4*)(pp + c);
    const u16* pb = (const u16*)&pv;
    float rr[8] = {r0.x, r0.y, r0.z, r0.w, r1.x, r1.y, r1.z, r1.w};
#pragma unroll
    for (int j = 0; j < 8; j++) {
      x[j] = rr[j] + g * bf2f(pb[j]);
      s += x[j]; q += x[j] * x[j];
    }
  }
#pragma unroll
  for (int o = 32; o > 0; o >>= 1) { s += __shfl_xor(s, o, 64); q += __shfl_xor(q, o, 64); }
  const float mean = s * (1.0f / DIM);
  const float var = q * (1.0f / DIM) - mean * mean;
  const float rstd = rsqrtf(var + 1e-5f);
  if (act) {
    float4 ga0 = *(const float4*)(gamma + c);
    float4 ga1 = *(const float4*)(gamma + c + 4);
    float4 be0 = *(const float4*)(beta + c);
    float4 be1 = *(const float4*)(beta + c + 4);
    float4 o0, o1;
    o0.x = (x[0] - mean) * rstd * ga0.x + be0.x;
    o0.y = (x[1] - mean) * rstd * ga0.y + be0.y;
    o0.z = (x[2] - mean) * rstd * ga0.z + be0.z;
    o0.w = (x[3] - mean) * rstd * ga0.w + be0.w;
    o1.x = (x[4] - mean) * rstd * ga1.x + be1.x;
    o1.y = (x[5] - mean) * rstd * ga1.y + be1.y;
    o1.z = (x[6] - mean) * rstd * ga1.z + be1.z;
    o1.w = (x[7] - mean) * rstd * ga1.w + be1.w;
    *(float4*)(op + c) = o0;
    *(float4*)(op + c + 4) = o1;
  }
}

// fp32 [rows,400] -> bf16 [rows,448], zero-padded cols 400..447.
// One 8-col segment per thread; segments are either fully real (cs+8<=400)
// or fully pad (cs>=400) since 400 % 8 == 0. float4 loads, uint4 store.
__global__ __launch_bounds__(256)
void cvt_pad(const float* __restrict__ src, u16* __restrict__ dst)
{
  const long g = (long)blockIdx.x * 256 + threadIdx.x;
  const long row = g / 56;
  const int cs = (int)(g % 56) * 8;
  __align__(16) u16 o[8];
  if (cs + 8 <= DIM) {
    float4 r0 = *(const float4*)(src + row * DIM + cs);
    float4 r1 = *(const float4*)(src + row * DIM + cs + 4);
    float rr[8] = {r0.x, r0.y, r0.z, r0.w, r1.x, r1.y, r1.z, r1.w};
#pragma unroll
    for (int j = 0; j < 8; j++) o[j] = f2bf(rr[j]);
  } else {
#pragma unroll
    for (int j = 0; j < 8; j++) o[j] = 0;
  }
  *(uint4*)(dst + row * KPAD + cs) = *(const uint4*)o;
}

// W [400,512] fp32 -> WT [512,448] bf16 (transposed, K zero-padded)
__global__ __launch_bounds__(256)
void cvt_wT(const float* __restrict__ W, u16* __restrict__ WT)
{
  const int g = blockIdx.x * 256 + threadIdx.x;  // 512*448 exact
  const int n = g / KPAD;
  const int kc = g % KPAD;
  WT[g] = f2bf(kc < DIM ? W[(long)kc * HID + n] : 0.0f);
}

// Wp [512,400] fp32 -> WT [512(N pad),512(K)] bf16 (transposed, N zero-padded)
__global__ __launch_bounds__(256)
void cvt_wpT(const float* __restrict__ Wp, u16* __restrict__ WT)
{
  const int g = blockIdx.x * 256 + threadIdx.x;  // 512*512 exact
  const int n = g / HID;
  const int kc = g % HID;
  WT[g] = f2bf(n < DIM ? Wp[(long)kc * DIM + n] : 0.0f);
}

extern "C" void kernel_launch(void* const* d_in, const int* in_sizes, int n_in,
                              void* d_out, int out_size, void* d_ws, size_t ws_size,
                              hipStream_t stream)
{
  const float* rgb  = (const float*)d_in[0];
  const float* pose = (const float*)d_in[1];
  const float* Wq   = (const float*)d_in[2];
  const float* bq   = (const float*)d_in[3];
  const float* Wk   = (const float*)d_in[4];
  const float* bk   = (const float*)d_in[5];
  const float* Wv   = (const float*)d_in[6];
  const float* bv   = (const float*)d_in[7];
  const float* Wp   = (const float*)d_in[8];
  const float* bp   = (const float*)d_in[9];
  const float* gam  = (const float*)d_in[10];
  const float* bet  = (const float*)d_in[11];
  const float* gate = (const float*)d_in[12];
  float* outp = (float*)d_out;
  char* ws = (char*)d_ws;

  // Workspace layout (~390 MB total, with lifetime-based reuse):
  //  [0, 58.7M)        rgbp (dies after QKV)   } reused later by outb/projb
  //  [58.7M, 117.4M)   posep (dies after QKV)  }
  //  outb  = [0, 67.1M)        written in PV GEMM (after rgbp/posep dead)
  //  projb = [67.1M, 119.5M)
  //  [119.5M, 121.4M)  WqT/WkT/WvT/WpT
  //  [121.4M, 188.5M)  q   ; [188.5M, 255.7M) k
  //  [255.7M, 322.8M)  v  -> reused as scores chunk after transpose
  //  [322.8M, 389.9M)  vT
  const size_t SZ_PAD = (size_t)MROWS * KPAD * 2;        // 58,720,256
  const size_t SZ_SH  = (size_t)MROWS * HID * 2;         // 67,108,864
  u16* rgbp  = (u16*)(ws + 0);
  u16* posep = (u16*)(ws + SZ_PAD);
  u16* outb  = (u16*)(ws + 0);          // reuse of rgbp/posep zone
  u16* projb = (u16*)(ws + SZ_SH);
  size_t off = 119537664;
  u16* wqT = (u16*)(ws + off); off += (size_t)HID * KPAD * 2;
  u16* wkT = (u16*)(ws + off); off += (size_t)HID * KPAD * 2;
  u16* wvT = (u16*)(ws + off); off += (size_t)HID * KPAD * 2;
  u16* wpT = (u16*)(ws + off); off += (size_t)HID * HID * 2;
  u16* qb  = (u16*)(ws + off); off += SZ_SH;
  u16* kb  = (u16*)(ws + off); off += SZ_SH;
  u16* vb  = (u16*)(ws + off);
  u16* scb = vb;                        // scores chunk overlays v (v dead post-transpose)
  off += SZ_SH;
  u16* vTb = (u16*)(ws + off); off += SZ_SH;

  // --- input conversion / packing ---
  cvt_pad<<<14336, 256, 0, stream>>>(rgb, rgbp);
  cvt_pad<<<14336, 256, 0, stream>>>(pose, posep);
  cvt_wT<<<896, 256, 0, stream>>>(Wq, wqT);
  cvt_wT<<<896, 256, 0, stream>>>(Wk, wkT);
  cvt_wT<<<896, 256, 0, stream>>>(Wv, wvT);
  cvt_wpT<<<1024, 256, 0, stream>>>(Wp, wpT);

  // --- QKV projections: [65536,448] @ [512,448]^T ---
  dim3 gQ(MROWS / 128, HID / 128, 1);   // (512,4)
  gemm_bt<<<gQ, 256, 0, stream>>>(rgbp,  wqT, qb, bq, KPAD, KPAD, KPAD, HID, HID, 1.0f, 0, 0, 0);
  gemm_bt<<<gQ, 256, 0, stream>>>(posep, wkT, kb, bk, KPAD, KPAD, KPAD, HID, HID, 1.0f, 0, 0, 0);
  gemm_bt<<<gQ, 256, 0, stream>>>(posep, wvT, vb, bv, KPAD, KPAD, KPAD, HID, HID, 1.0f, 0, 0, 0);

  // --- v -> vT per batch ---
  dim3 gT(S_LEN / 64, HID / 64, BATCH); // (32,8,32)
  transpose_hs<<<gT, 256, 0, stream>>>(vb, vTb);

  // --- attention, chunked over batches (scores chunk stays L3-resident) ---
  const long sSH = (long)S_LEN * HID;     // 1,048,576
  const long sSS = (long)S_LEN * S_LEN;   // 4,194,304
  for (int c = 0; c < BATCH / NB_CHUNK; c++) {
    const size_t bo = (size_t)c * NB_CHUNK;
    dim3 g2(S_LEN / 128, S_LEN / 128, NB_CHUNK);  // (16,16,8)
    gemm_bt<<<g2, 256, 0, stream>>>(qb + bo * sSH, kb + bo * sSH, scb, nullptr,
                                    HID, HID, HID, S_LEN, S_LEN, SCALE_QK, sSH, sSH, sSS);
    softmax_rows<<<NB_CHUNK * S_LEN / 4, 256, 0, stream>>>(scb);
    dim3 g4(S_LEN / 128, HID / 128, NB_CHUNK);    // (16,4,8)
    gemm_bt<<<g4, 256, 0, stream>>>(scb, vTb + bo * sSH, outb + bo * sSH, nullptr,
                                    S_LEN, S_LEN, S_LEN, HID, HID, 1.0f, sSS, sSH, sSH);
  }

  // --- output projection: [65536,512] @ [512(400 pad),512]^T + bp ---
  gemm_bt<<<gQ, 256, 0, stream>>>(outb, wpT, projb, bp, HID, HID, HID, DIM, DIM, 1.0f, 0, 0, 0);

  // --- gated residual + LayerNorm (fp32 rgb path keeps residual exact) ---
  fuse_ln<<<MROWS / 4, 256, 0, stream>>>(rgb, projb, gate, gam, bet, outp);
}